// Round 14
// baseline (276.645 us; speedup 1.0000x reference)
//
#include <hip/hip_runtime.h>
#include <math.h>

typedef __bf16 bf16x8 __attribute__((ext_vector_type(8)));
typedef __bf16 bf16x4 __attribute__((ext_vector_type(4)));
typedef float  f32x4  __attribute__((ext_vector_type(4)));

// N=2, Q=1600, K=100 (pad 112), C=256, h=8, d=32.

// ---- workspace layout (float offsets), total 2,548,512 f32 = 10.19 MB ----
#define WS_KH    0u        // [200][256] f32 k projection                 -> 51200
#define WS_VH    51200u    // [200][256] f32 v projection                 -> 102400
#define WS_EWT   102400u   // [260][256] f32 embed_w TRANSPOSED (j-major) -> 168960
#define WS_QHB   168960u   // bf16 [3200][256] scaled q projection        -> 578560
#define WS_BIASB 578560u   // bf16 [3200][112][8] rel-pos bias            -> 2012160
#define WS_KEB   2012160u  // bf16 [200][264] key sin/cos table (pad 264) -> 2038560
#define WS_W1B   2038560u  // bf16 [256][256] pos_w1                      -> 2071328
#define WS_W2PB  2071328u  // bf16 [16][256] pos_w2 padded                -> 2073376
#define WS_QEB   2073376u  // bf16 [3200][256] query sin/cos table        -> 2482976
#define WS_OWT   2482976u  // [256][256] f32 out_proj_w TRANSPOSED        -> 2548512

__device__ __forceinline__ float rdlane(float v, int l) {
  return __uint_as_float(__builtin_amdgcn_readlane(__float_as_uint(v), l));
}

__device__ __forceinline__ unsigned packbf(float a, float b) {
  unsigned short ua = __builtin_bit_cast(unsigned short, (__bf16)a);
  unsigned short ub = __builtin_bit_cast(unsigned short, (__bf16)b);
  return (unsigned)ua | ((unsigned)ub << 16);
}

// ---------------------------------------------------------------------------
// prep (r11 form, unchanged — best measured non-bias config)
__global__ __launch_bounds__(256, 2) void prep_kernel(
    const float* __restrict__ qfeat, const float* __restrict__ kfeat,
    const float* __restrict__ kpos, const float* __restrict__ qpos,
    const float* __restrict__ ipw, const float* __restrict__ ipb,
    const float* __restrict__ pos_w1, const float* __restrict__ pos_w2,
    const float* __restrict__ ow, const float* __restrict__ ew,
    float* __restrict__ ws)
{
  __shared__ float x[8 * 256];
  int bid = blockIdx.x, t = threadIdx.x;

  if (bid < 50) {
    int r = bid * 4 + (t >> 6);
    int u = t & 63;
    float p0 = kpos[r * 2 + 0], p1 = kpos[r * 2 + 1];
    __bf16* keb = (__bf16*)(ws + WS_KEB);
    bf16x4 o;
#pragma unroll
    for (int j = 0; j < 4; j++) {
      int col = u * 4 + j;
      int c = col >> 7, i = (col & 127) >> 1;
      float p = c ? p1 : p0;
      float inv = exp2f((float)i * (-13.287712379549449f / 64.0f));
      float v = p * inv;
      o[j] = (__bf16)((col & 1) ? __cosf(v) : __sinf(v));
    }
    *(bf16x4*)(keb + r * 264 + u * 4) = o;
  } else if (bid < 114) {
    int idx = (bid - 50) * 1024 + t * 4;
    float4 v = *(const float4*)(pos_w1 + idx);
    bf16x4 o; o[0] = (__bf16)v.x; o[1] = (__bf16)v.y; o[2] = (__bf16)v.z; o[3] = (__bf16)v.w;
    *(bf16x4*)((__bf16*)(ws + WS_W1B) + idx) = o;
  } else if (bid == 114) {
    __bf16* w2pb = (__bf16*)(ws + WS_W2PB);
    for (int i = 0; i < 16; i++) {
      int idx = t * 16 + i;
      w2pb[idx] = (idx < 2048) ? (__bf16)pos_w2[idx] : (__bf16)0.0f;
    }
  } else if (bid < 147) {
    return;
  } else if (bid < 547) {
    int r0 = (bid - 147) * 8;
    for (int i = t; i < 2048; i += 256) x[i] = qfeat[(unsigned)r0 * 256u + i];
    __syncthreads();
    float acc[8]; float bq = ipb[t];
#pragma unroll
    for (int rr = 0; rr < 8; rr++) acc[rr] = bq;
    const float* wrow = ipw + (unsigned)t * 256u;
    for (int j = 0; j < 256; j += 4) {
      float4 w4 = *(const float4*)(wrow + j);
#pragma unroll
      for (int rr = 0; rr < 8; rr++) {
        float4 x4 = *(const float4*)(x + rr * 256 + j);
        acc[rr] = fmaf(x4.x, w4.x, fmaf(x4.y, w4.y, fmaf(x4.z, w4.z, fmaf(x4.w, w4.w, acc[rr]))));
      }
    }
    __bf16* qhb = (__bf16*)(ws + WS_QHB);
#pragma unroll
    for (int rr = 0; rr < 8; rr++)
      qhb[(unsigned)(r0 + rr) * 256u + t] = (__bf16)(acc[rr] * 0.17677669529663687f);
  } else if (bid < 579) {
    int b2 = bid - 547; int n = b2 >> 4, tile = b2 & 15;
    int r0l = tile * 7; int cnt = 100 - r0l; if (cnt > 7) cnt = 7; if (cnt <= 0) return;
    int r0 = n * 100 + r0l;
    for (int i = t; i < cnt * 256; i += 256) x[i] = kfeat[(unsigned)r0 * 256u + i];
    __syncthreads();
    float ak[7], av[7]; float bk = ipb[256 + t], bv = ipb[512 + t];
#pragma unroll
    for (int rr = 0; rr < 7; rr++) { ak[rr] = bk; av[rr] = bv; }
    const float* wkr = ipw + (unsigned)(256 + t) * 256u;
    const float* wvr = ipw + (unsigned)(512 + t) * 256u;
    for (int j = 0; j < 256; j += 4) {
      float4 wk4 = *(const float4*)(wkr + j);
      float4 wv4 = *(const float4*)(wvr + j);
#pragma unroll
      for (int rr = 0; rr < 7; rr++) {
        float4 x4 = *(const float4*)(x + rr * 256 + j);
        ak[rr] = fmaf(x4.x, wk4.x, fmaf(x4.y, wk4.y, fmaf(x4.z, wk4.z, fmaf(x4.w, wk4.w, ak[rr]))));
        av[rr] = fmaf(x4.x, wv4.x, fmaf(x4.y, wv4.y, fmaf(x4.z, wv4.z, fmaf(x4.w, wv4.w, av[rr]))));
      }
    }
    for (int rr = 0; rr < 7; rr++) {
      if (rr < cnt) {
        ws[WS_KH + (unsigned)(r0 + rr) * 256u + t] = ak[rr];
        ws[WS_VH + (unsigned)(r0 + rr) * 256u + t] = av[rr];
      }
    }
  } else if (bid < 1379) {
    int r = (bid - 579) * 4 + (t >> 6);
    int u = t & 63;
    float p0 = qpos[r * 2 + 0], p1 = qpos[r * 2 + 1];
    __bf16* qeb = (__bf16*)(ws + WS_QEB);
    bf16x4 o;
#pragma unroll
    for (int j = 0; j < 4; j++) {
      int col = u * 4 + j;
      int c = col >> 7, i = (col & 127) >> 1;
      float p = c ? p1 : p0;
      float inv = exp2f((float)i * (-13.287712379549449f / 64.0f));
      float v = p * inv;
      o[j] = (__bf16)((col & 1) ? __cosf(v) : __sinf(v));
    }
    *(bf16x4*)(qeb + r * 256 + u * 4) = o;
  } else if (bid < 1395) {
    __shared__ float tile[64][65];
    int b = bid - 1379;
    int row0 = (b >> 2) * 64, col0 = (b & 3) * 64;
    int l = t & 63, gq = t >> 6;
#pragma unroll
    for (int i = 0; i < 16; i++) {
      int r = gq * 16 + i;
      tile[r][l] = ow[(unsigned)(row0 + r) * 256u + col0 + l];
    }
    __syncthreads();
#pragma unroll
    for (int i = 0; i < 16; i++) {
      int r = gq * 16 + i;
      ws[WS_OWT + (unsigned)(col0 + r) * 256u + row0 + l] = tile[l][r];
    }
  } else {
    __shared__ float tile[64][65];
    int b = bid - 1395;
    int row0 = (b / 5) * 64, col0 = (b % 5) * 64;
    int l = t & 63, gq = t >> 6;
#pragma unroll
    for (int i = 0; i < 16; i++) {
      int r = gq * 16 + i;
      int cin = col0 + l;
      tile[r][l] = (cin < 258) ? ew[(unsigned)(row0 + r) * 258u + cin] : 0.0f;
    }
    __syncthreads();
#pragma unroll
    for (int i = 0; i < 16; i++) {
      int r = gq * 16 + i;
      int j = col0 + r;
      if (j < 260) ws[WS_EWT + (unsigned)j * 256u + row0 + l] = tile[l][r];
    }
  }
}

// ---------------------------------------------------------------------------
// bias kernel v15 = r13 (94.4us, banked) + w2f HOISTED to persistent regs.
// r13's gemm2 re-loaded the loop-invariant 512B w2pb operand from L2 every
// phase (5x/block) on exactly the waves (wq==0) that run gemm2+GEMM1 and
// gate the barrier — ~200cy x 5 on the slowest waves' critical path.
// Hoist: 32 VGPRs loaded once per block. Regs ~160 < 256 @ (512,2); no
// spill expected (revert check: WRITE_SIZE must stay ~10MB).
// Structure history: occupancy-invariant (r7/r12), drain-free (r8),
// setprio'd (r13). This is the last surgical lever in the formulation.
__global__ __launch_bounds__(512, 2) void bias_kernel(
    const float* __restrict__ pos_b1, const float* __restrict__ pos_b2,
    float* __restrict__ ws)
{
  __shared__ __align__(16) char qe_smem[2][32768];    // [64 q][512B] swizzled
  __shared__ __align__(16) char hid_smem[2][32768];   // [64 q][512B] swizzled
  __shared__ __align__(16) __bf16 keb_s[256];

  int bid = blockIdx.x;           // 0..999 = nk(200) x qgroup(5)
  int nk = bid / 5, g = bid - nk * 5;
  int n = nk / 100, k = nk - n * 100;
  int qbase = n * 1600 + g * 320;
  int t = threadIdx.x;
  int lane = t & 63, w = t >> 6;        // w 0..7
  int wc = w & 3, wq = w >> 2;          // c-quadrant, q-half
  int l15 = lane & 15, quad = lane >> 4;

  const __bf16* keb = (const __bf16*)(ws + WS_KEB) + (unsigned)nk * 264u;
  const __bf16* qeb = (const __bf16*)(ws + WS_QEB);
  const __bf16* w1b = (const __bf16*)(ws + WS_W1B);
  const __bf16* w2pb = (const __bf16*)(ws + WS_W2PB);
  __bf16* biasb = (__bf16*)(ws + WS_BIASB);

  if (t < 32) *(bf16x8*)(keb_s + t * 8) = *(const bf16x8*)(keb + t * 8);

  int sr = t >> 3, ssub = t & 7, sswz = (sr & 7) << 4;
  {
    const __bf16* src = qeb + (unsigned)(qbase + sr) * 256u + ssub * 32;
    char* dst = qe_smem[0] + sr * 512;
#pragma unroll
    for (int u = 0; u < 4; u++) {
      bf16x8 v = *(const bf16x8*)(src + u * 8);
      *(bf16x8*)(dst + ((ssub * 64 + u * 16) ^ sswz)) = v;
    }
  }

  int xm = (l15 & 7) << 4;
  int colx[8];
#pragma unroll
  for (int kc = 0; kc < 8; kc++) colx[kc] = ((kc * 64 + quad * 16) ^ xm);
  const __bf16* w1p = w1b + (unsigned)(wc * 64 + l15) * 256u + quad * 8;

  float b1a[4][4];
#pragma unroll
  for (int ct = 0; ct < 4; ct++)
#pragma unroll
    for (int r = 0; r < 4; r++) b1a[ct][r] = pos_b1[wc * 64 + ct * 16 + quad * 4 + r];
  float b2v[4];
#pragma unroll
  for (int r = 0; r < 4; r++) b2v[r] = pos_b2[(quad * 4 + r) & 7];

  // w2 B-frags hoisted: loop-invariant, resident all block (32 VGPRs)
  bf16x8 w2fr[8];
#pragma unroll
  for (int kc = 0; kc < 8; kc++)
    w2fr[kc] = *(const bf16x8*)(w2pb + (unsigned)l15 * 256u + kc * 32 + quad * 8);

  f32x4 zero4; zero4[0] = 0.f; zero4[1] = 0.f; zero4[2] = 0.f; zero4[3] = 0.f;

  __syncthreads();   // keb_s + qe tile0 ready

  bf16x8 af[8][4];
#pragma unroll
  for (int kc = 0; kc < 8; kc++) {
    bf16x8 ke8 = *(const bf16x8*)(keb_s + kc * 32 + quad * 8);
#pragma unroll
    for (int ct = 0; ct < 4; ct++) {
      bf16x8 w8 = *(const bf16x8*)(w1p + ct * 4096 + kc * 32);
      bf16x8 a;
#pragma unroll
      for (int p2 = 0; p2 < 4; p2++) {
        float we = (float)w8[2 * p2], wo = (float)w8[2 * p2 + 1];
        float sk = (float)ke8[2 * p2], ck = (float)ke8[2 * p2 + 1];
        a[2 * p2]     = (__bf16)fmaf(wo, sk, -(we * ck));
        a[2 * p2 + 1] = (__bf16)fmaf(we, sk, wo * ck);
      }
      af[kc][ct] = a;
    }
  }

  unsigned long long bias_pk[5];

  auto gemm2 = [&](int tg) {
    int row = wc * 16 + l15;
    const char* hbase = hid_smem[tg & 1] + row * 512;
    int hxm = (l15 & 7) << 4;
    f32x4 acc2 = zero4;
    __builtin_amdgcn_s_setprio(1);    // T5: MFMA cluster
#pragma unroll
    for (int kc = 0; kc < 8; kc++) {
      bf16x8 hf = *(const bf16x8*)(hbase + ((kc * 64 + quad * 16) ^ hxm));
      acc2 = __builtin_amdgcn_mfma_f32_16x16x32_bf16(w2fr[kc], hf, acc2, 0, 0, 0);
    }
    __builtin_amdgcn_s_setprio(0);
    unsigned lo = packbf(acc2[0] + b2v[0], acc2[1] + b2v[1]);
    unsigned hi = packbf(acc2[2] + b2v[2], acc2[3] + b2v[3]);
    return (unsigned long long)lo | ((unsigned long long)hi << 32);
  };

#pragma unroll
  for (int tt = 0; tt < 5; tt++) {
    bf16x8 qv[4];
    if (tt < 4) {
      const __bf16* src = qeb + (unsigned)(qbase + (tt + 1) * 64 + sr) * 256u + ssub * 32;
#pragma unroll
      for (int u = 0; u < 4; u++) qv[u] = *(const bf16x8*)(src + u * 8);
    }

    if (tt > 0 && wq == 0) bias_pk[tt - 1] = gemm2(tt - 1);

    f32x4 acc[4][2];
#pragma unroll
    for (int ct = 0; ct < 4; ct++)
#pragma unroll
      for (int nt = 0; nt < 2; nt++) acc[ct][nt] = zero4;

    __builtin_amdgcn_s_setprio(1);    // T5: GEMM1 MFMA cluster
#pragma unroll
    for (int kc = 0; kc < 8; kc++) {
#pragma unroll
      for (int nt = 0; nt < 2; nt++) {
        int row = wq * 32 + nt * 16 + l15;
        bf16x8 qf = *(const bf16x8*)(qe_smem[tt & 1] + row * 512 + colx[kc]);
        acc[0][nt] = __builtin_amdgcn_mfma_f32_16x16x32_bf16(af[kc][0], qf, acc[0][nt], 0, 0, 0);
        acc[1][nt] = __builtin_amdgcn_mfma_f32_16x16x32_bf16(af[kc][1], qf, acc[1][nt], 0, 0, 0);
        acc[2][nt] = __builtin_amdgcn_mfma_f32_16x16x32_bf16(af[kc][2], qf, acc[2][nt], 0, 0, 0);
        acc[3][nt] = __builtin_amdgcn_mfma_f32_16x16x32_bf16(af[kc][3], qf, acc[3][nt], 0, 0, 0);
      }
    }
    __builtin_amdgcn_s_setprio(0);

#pragma unroll
    for (int ct = 0; ct < 4; ct++) {
#pragma unroll
      for (int nt = 0; nt < 2; nt++) {
        int q = wq * 32 + nt * 16 + l15;
        unsigned lo = packbf(fmaxf(acc[ct][nt][0] + b1a[ct][0], 0.f),
                             fmaxf(acc[ct][nt][1] + b1a[ct][1], 0.f));
        unsigned hi = packbf(fmaxf(acc[ct][nt][2] + b1a[ct][2], 0.f),
                             fmaxf(acc[ct][nt][3] + b1a[ct][3], 0.f));
        int cbyte = wc * 128 + ct * 32 + quad * 8;
        char* p = hid_smem[tt & 1] + q * 512 + (cbyte ^ ((q & 7) << 4));
        *(unsigned long long*)p = (unsigned long long)lo | ((unsigned long long)hi << 32);
      }
    }

    if (tt < 4) {
      char* dst = qe_smem[(tt + 1) & 1] + sr * 512;
#pragma unroll
      for (int u = 0; u < 4; u++)
        *(bf16x8*)(dst + ((ssub * 64 + u * 16) ^ sswz)) = qv[u];
    }

    __syncthreads();
  }

  if (wq == 0) {
    bias_pk[4] = gemm2(4);
    if (quad < 2) {
      int row = wc * 16 + l15;
#pragma unroll
      for (int tg = 0; tg < 5; tg++) {
        int qg = qbase + tg * 64 + row;
        *(unsigned long long*)(biasb + (unsigned)qg * 896u + (unsigned)k * 8u + quad * 4)
            = bias_pk[tg];
      }
    }
  }
}

// ---------------------------------------------------------------------------
// attn kernel (r11 form, unchanged): owT/ewT column reads; rdlane broadcast.
__global__ __launch_bounds__(256, 4) void attn_kernel(
    const float* __restrict__ qfeat, const float* __restrict__ qpos,
    const float* __restrict__ kpos,
    const float* __restrict__ out_b,
    const float* __restrict__ embed_b, const float* __restrict__ ptw,
    const float* __restrict__ ws, float* __restrict__ out)
{
  __shared__ float qh_s[4 * 8 * 36];
  __shared__ float attn_s[4 * 8 * 116];
  __shared__ float ctx_s[4 * 264];
  __shared__ float cat_s[4 * 264];
  __shared__ float aw_s[4 * 104];

  int bid = blockIdx.x;
  int qg0 = bid * 4;
  int n = bid / 400;
  int t = threadIdx.x;

  const __bf16* qhb = (const __bf16*)(ws + WS_QHB);
  const __bf16* biasb = (const __bf16*)(ws + WS_BIASB);
  const float* kh = ws + WS_KH;
  const float* vh = ws + WS_VH;

  for (int i = t; i < 1024; i += 256) {
    int q = i >> 8, c = i & 255;
    qh_s[(q * 8 + (c >> 5)) * 36 + (c & 31)] = (float)qhb[(unsigned)(qg0 + q) * 256u + c];
  }
  __syncthreads();

  for (int i = 0; i < 4; i++) {
    int p = t + i * 256;
    if (p < 800) {
      int k = p >> 3, h = p & 7;
      const float4* kf = (const float4*)(kh + (unsigned)(n * 100 + k) * 256u + h * 32);
      float4 kv[8];
#pragma unroll
      for (int dd = 0; dd < 8; dd++) kv[dd] = kf[dd];
#pragma unroll
      for (int q = 0; q < 4; q++) {
        const float4* qf = (const float4*)(qh_s + (q * 8 + h) * 36);
        float s = (float)biasb[((unsigned)(qg0 + q) * 112u + k) * 8u + h];
#pragma unroll
        for (int dd = 0; dd < 8; dd++) {
          float4 qv = qf[dd];
          s += kv[dd].x * qv.x + kv[dd].y * qv.y + kv[dd].z * qv.z + kv[dd].w * qv.w;
        }
        attn_s[(q * 8 + h) * 116 + k] = s;
      }
    }
  }
  __syncthreads();

  {
    int q = t >> 6, h = (t >> 3) & 7, j = t & 7;
    float* row = attn_s + (q * 8 + h) * 116;
    float mx = -1e30f;
    for (int k = j; k < 100; k += 8) mx = fmaxf(mx, row[k]);
    mx = fmaxf(mx, __shfl_xor(mx, 1, 8));
    mx = fmaxf(mx, __shfl_xor(mx, 2, 8));
    mx = fmaxf(mx, __shfl_xor(mx, 4, 8));
    float sum = 0.f;
    for (int k = j; k < 100; k += 8) { float e = __expf(row[k] - mx); row[k] = e; sum += e; }
    sum += __shfl_xor(sum, 1, 8);
    sum += __shfl_xor(sum, 2, 8);
    sum += __shfl_xor(sum, 4, 8);
    float inv = 1.0f / sum;
    for (int k = j; k < 100; k += 8) row[k] *= inv;
  }
  __syncthreads();

  for (int p = t; p < 416; p += 256) {
    int q = p / 104, k = p % 104;
    if (k < 100) {
      float s = 0.f;
#pragma unroll
      for (int h = 0; h < 8; h++) s += attn_s[(q * 8 + h) * 116 + k];
      aw_s[q * 104 + k] = s * 0.125f;
    }
  }
  {
    int c = t, h = c >> 5;
    float a0 = 0.f, a1 = 0.f, a2 = 0.f, a3 = 0.f;
    const float* vp = vh + (unsigned)(n * 100) * 256u + c;
    const float* r0 = attn_s + (0 * 8 + h) * 116;
    const float* r1 = attn_s + (1 * 8 + h) * 116;
    const float* r2 = attn_s + (2 * 8 + h) * 116;
    const float* r3 = attn_s + (3 * 8 + h) * 116;
#pragma unroll 4
    for (int k = 0; k < 100; k++) {
      float vv = vp[(unsigned)k * 256u];
      a0 = fmaf(r0[k], vv, a0);
      a1 = fmaf(r1[k], vv, a1);
      a2 = fmaf(r2[k], vv, a2);
      a3 = fmaf(r3[k], vv, a3);
    }
    ctx_s[0 * 264 + c] = a0; ctx_s[1 * 264 + c] = a1;
    ctx_s[2 * 264 + c] = a2; ctx_s[3 * 264 + c] = a3;
  }
  __syncthreads();

  if (t < 8) {
    int q = t >> 1, cd = t & 1;
    float qp = qpos[(qg0 + q) * 2 + cd];
    float s = 0.f;
    for (int k = 0; k < 100; k++)
      s = fmaf(aw_s[q * 104 + k], kpos[(n * 100 + k) * 2 + cd] - qp, s);
    float so = __shfl_xor(s, 1, 2);
    if (cd == 0) cat_s[q * 264 + 256] = ptw[0] * s + ptw[1] * so;
    else         cat_s[q * 264 + 257] = ptw[2] * so + ptw[3] * s;
  }

  {
    int c = t, lane = t & 63;
    float ob = out_b[c];
    float acc0 = ob, acc1 = ob, acc2 = ob, acc3 = ob;
    const float* wcol = ws + WS_OWT + c;
    for (int ch = 0; ch < 4; ch++) {
      float v0 = ctx_s[0 * 264 + ch * 64 + lane];
      float v1 = ctx_s[1 * 264 + ch * 64 + lane];
      float v2 = ctx_s[2 * 264 + ch * 64 + lane];
      float v3 = ctx_s[3 * 264 + ch * 64 + lane];
#pragma unroll 4
      for (int j4 = 0; j4 < 16; j4++) {
        int jg = ch * 64 + j4 * 4;
        float w0 = wcol[(unsigned)(jg + 0) * 256u];
        float w1 = wcol[(unsigned)(jg + 1) * 256u];
        float w2 = wcol[(unsigned)(jg + 2) * 256u];
        float w3 = wcol[(unsigned)(jg + 3) * 256u];
        int jb = j4 * 4;
        acc0 = fmaf(rdlane(v0, jb + 0), w0, acc0);
        acc1 = fmaf(rdlane(v1, jb + 0), w0, acc1);
        acc2 = fmaf(rdlane(v2, jb + 0), w0, acc2);
        acc3 = fmaf(rdlane(v3, jb + 0), w0, acc3);
        acc0 = fmaf(rdlane(v0, jb + 1), w1, acc0);
        acc1 = fmaf(rdlane(v1, jb + 1), w1, acc1);
        acc2 = fmaf(rdlane(v2, jb + 1), w1, acc2);
        acc3 = fmaf(rdlane(v3, jb + 1), w1, acc3);
        acc0 = fmaf(rdlane(v0, jb + 2), w2, acc0);
        acc1 = fmaf(rdlane(v1, jb + 2), w2, acc1);
        acc2 = fmaf(rdlane(v2, jb + 2), w2, acc2);
        acc3 = fmaf(rdlane(v3, jb + 2), w2, acc3);
        acc0 = fmaf(rdlane(v0, jb + 3), w3, acc0);
        acc1 = fmaf(rdlane(v1, jb + 3), w3, acc1);
        acc2 = fmaf(rdlane(v2, jb + 3), w3, acc2);
        acc3 = fmaf(rdlane(v3, jb + 3), w3, acc3);
      }
    }
    cat_s[0 * 264 + c] = fmaxf(qfeat[(unsigned)(qg0 + 0) * 256u + c] + acc0, 0.f);
    cat_s[1 * 264 + c] = fmaxf(qfeat[(unsigned)(qg0 + 1) * 256u + c] + acc1, 0.f);
    cat_s[2 * 264 + c] = fmaxf(qfeat[(unsigned)(qg0 + 2) * 256u + c] + acc2, 0.f);
    cat_s[3 * 264 + c] = fmaxf(qfeat[(unsigned)(qg0 + 3) * 256u + c] + acc3, 0.f);
  }
  __syncthreads();

  {
    int c = t, lane = t & 63;
    float eb = embed_b[c];
    float acc0 = eb, acc1 = eb, acc2 = eb, acc3 = eb;
    const float* ecol = ws + WS_EWT + c;
    for (int ch = 0; ch < 4; ch++) {
      float v0 = cat_s[0 * 264 + ch * 64 + lane];
      float v1 = cat_s[1 * 264 + ch * 64 + lane];
      float v2 = cat_s[2 * 264 + ch * 64 + lane];
      float v3 = cat_s[3 * 264 + ch * 64 + lane];
#pragma unroll 4
      for (int j4 = 0; j4 < 16; j4++) {
        int jg = ch * 64 + j4 * 4;
        float w0 = ecol[(unsigned)(jg + 0) * 256u];
        float w1 = ecol[(unsigned)(jg + 1) * 256u];
        float w2 = ecol[(unsigned)(jg + 2) * 256u];
        float w3 = ecol[(unsigned)(jg + 3) * 256u];
        int jb = j4 * 4;
        acc0 = fmaf(rdlane(v0, jb + 0), w0, acc0);
        acc1 = fmaf(rdlane(v1, jb + 0), w0, acc1);
        acc2 = fmaf(rdlane(v2, jb + 0), w0, acc2);
        acc3 = fmaf(rdlane(v3, jb + 0), w0, acc3);
        acc0 = fmaf(rdlane(v0, jb + 1), w1, acc0);
        acc1 = fmaf(rdlane(v1, jb + 1), w1, acc1);
        acc2 = fmaf(rdlane(v2, jb + 1), w1, acc2);
        acc3 = fmaf(rdlane(v3, jb + 1), w1, acc3);
        acc0 = fmaf(rdlane(v0, jb + 2), w2, acc0);
        acc1 = fmaf(rdlane(v1, jb + 2), w2, acc1);
        acc2 = fmaf(rdlane(v2, jb + 2), w2, acc2);
        acc3 = fmaf(rdlane(v3, jb + 2), w2, acc3);
        acc0 = fmaf(rdlane(v0, jb + 3), w3, acc0);
        acc1 = fmaf(rdlane(v1, jb + 3), w3, acc1);
        acc2 = fmaf(rdlane(v2, jb + 3), w3, acc2);
        acc3 = fmaf(rdlane(v3, jb + 3), w3, acc3);
      }
    }
    float wtx = ecol[256u * 256u];
    float wty = ecol[257u * 256u];
    acc0 += cat_s[0 * 264 + 256] * wtx + cat_s[0 * 264 + 257] * wty;
    acc1 += cat_s[1 * 264 + 256] * wtx + cat_s[1 * 264 + 257] * wty;
    acc2 += cat_s[2 * 264 + 256] * wtx + cat_s[2 * 264 + 257] * wty;
    acc3 += cat_s[3 * 264 + 256] * wtx + cat_s[3 * 264 + 257] * wty;
    out[(unsigned)(qg0 + 0) * 256u + c] = fmaxf(acc0, 0.f);
    out[(unsigned)(qg0 + 1) * 256u + c] = fmaxf(acc1, 0.f);
    out[(unsigned)(qg0 + 2) * 256u + c] = fmaxf(acc2, 0.f);
    out[(unsigned)(qg0 + 3) * 256u + c] = fmaxf(acc3, 0.f);
  }
}

// ---------------------------------------------------------------------------
extern "C" void kernel_launch(void* const* d_in, const int* in_sizes, int n_in,
                              void* d_out, int out_size, void* d_ws, size_t ws_size,
                              hipStream_t stream)
{
  const float* query_feature  = (const float*)d_in[0];
  const float* query_position = (const float*)d_in[1];
  const float* key_feature    = (const float*)d_in[2];
  const float* key_position   = (const float*)d_in[3];
  const float* in_proj_w      = (const float*)d_in[4];
  const float* in_proj_b      = (const float*)d_in[5];
  const float* out_proj_w     = (const float*)d_in[6];
  const float* out_proj_b     = (const float*)d_in[7];
  const float* pos_w1         = (const float*)d_in[8];
  const float* pos_b1         = (const float*)d_in[9];
  const float* pos_w2         = (const float*)d_in[10];
  const float* pos_b2         = (const float*)d_in[11];
  const float* pos_trans_w    = (const float*)d_in[12];
  const float* embed_w        = (const float*)d_in[13];
  const float* embed_b        = (const float*)d_in[14];
  float* ws  = (float*)d_ws;
  float* out = (float*)d_out;

  hipLaunchKernelGGL(prep_kernel, dim3(1415), dim3(256), 0, stream,
                     query_feature, key_feature, key_position, query_position,
                     in_proj_w, in_proj_b, pos_w1, pos_w2,
                     out_proj_w, embed_w, ws);
  hipLaunchKernelGGL(bias_kernel, dim3(1000), dim3(512), 0, stream,
                     pos_b1, pos_b2, ws);
  hipLaunchKernelGGL(attn_kernel, dim3(800), dim3(256), 0, stream,
                     query_feature, query_position, key_position,
                     out_proj_b, embed_b, pos_trans_w,
                     ws, out);
}

// Round 16
// 261.054 us; speedup vs baseline: 1.0597x; 1.0597x over previous
//
#include <hip/hip_runtime.h>
#include <math.h>

typedef __bf16 bf16x8 __attribute__((ext_vector_type(8)));
typedef __bf16 bf16x4 __attribute__((ext_vector_type(4)));
typedef float  f32x4  __attribute__((ext_vector_type(4)));

// N=2, Q=1600, K=100 (pad 112), C=256, h=8, d=32.

// ---- workspace layout (float offsets), total 2,548,512 f32 = 10.19 MB ----
#define WS_KH    0u        // [200][256] f32 k projection                 -> 51200
#define WS_VH    51200u    // [200][256] f32 v projection                 -> 102400
#define WS_EWT   102400u   // [260][256] f32 embed_w TRANSPOSED (j-major) -> 168960
#define WS_QHB   168960u   // bf16 [3200][256] scaled q projection        -> 578560
#define WS_BIASB 578560u   // bf16 [3200][112][8] rel-pos bias            -> 2012160
#define WS_KEB   2012160u  // bf16 [200][264] key sin/cos table (pad 264) -> 2038560
#define WS_W1B   2038560u  // bf16 [256][256] pos_w1                      -> 2071328
#define WS_W2PB  2071328u  // bf16 [16][256] pos_w2 padded                -> 2073376
#define WS_QEB   2073376u  // bf16 [3200][256] query sin/cos table        -> 2482976
#define WS_OWT   2482976u  // [256][256] f32 out_proj_w TRANSPOSED        -> 2548512

__device__ __forceinline__ float rdlane(float v, int l) {
  return __uint_as_float(__builtin_amdgcn_readlane(__float_as_uint(v), l));
}

__device__ __forceinline__ unsigned packbf(float a, float b) {
  unsigned short ua = __builtin_bit_cast(unsigned short, (__bf16)a);
  unsigned short ub = __builtin_bit_cast(unsigned short, (__bf16)b);
  return (unsigned)ua | ((unsigned)ub << 16);
}

// ---------------------------------------------------------------------------
// prep (r11 form — best measured non-bias config)
__global__ __launch_bounds__(256, 2) void prep_kernel(
    const float* __restrict__ qfeat, const float* __restrict__ kfeat,
    const float* __restrict__ kpos, const float* __restrict__ qpos,
    const float* __restrict__ ipw, const float* __restrict__ ipb,
    const float* __restrict__ pos_w1, const float* __restrict__ pos_w2,
    const float* __restrict__ ow, const float* __restrict__ ew,
    float* __restrict__ ws)
{
  __shared__ float x[8 * 256];
  int bid = blockIdx.x, t = threadIdx.x;

  if (bid < 50) {
    int r = bid * 4 + (t >> 6);
    int u = t & 63;
    float p0 = kpos[r * 2 + 0], p1 = kpos[r * 2 + 1];
    __bf16* keb = (__bf16*)(ws + WS_KEB);
    bf16x4 o;
#pragma unroll
    for (int j = 0; j < 4; j++) {
      int col = u * 4 + j;
      int c = col >> 7, i = (col & 127) >> 1;
      float p = c ? p1 : p0;
      float inv = exp2f((float)i * (-13.287712379549449f / 64.0f));
      float v = p * inv;
      o[j] = (__bf16)((col & 1) ? __cosf(v) : __sinf(v));
    }
    *(bf16x4*)(keb + r * 264 + u * 4) = o;
  } else if (bid < 114) {
    int idx = (bid - 50) * 1024 + t * 4;
    float4 v = *(const float4*)(pos_w1 + idx);
    bf16x4 o; o[0] = (__bf16)v.x; o[1] = (__bf16)v.y; o[2] = (__bf16)v.z; o[3] = (__bf16)v.w;
    *(bf16x4*)((__bf16*)(ws + WS_W1B) + idx) = o;
  } else if (bid == 114) {
    __bf16* w2pb = (__bf16*)(ws + WS_W2PB);
    for (int i = 0; i < 16; i++) {
      int idx = t * 16 + i;
      w2pb[idx] = (idx < 2048) ? (__bf16)pos_w2[idx] : (__bf16)0.0f;
    }
  } else if (bid < 147) {
    return;
  } else if (bid < 547) {
    int r0 = (bid - 147) * 8;
    for (int i = t; i < 2048; i += 256) x[i] = qfeat[(unsigned)r0 * 256u + i];
    __syncthreads();
    float acc[8]; float bq = ipb[t];
#pragma unroll
    for (int rr = 0; rr < 8; rr++) acc[rr] = bq;
    const float* wrow = ipw + (unsigned)t * 256u;
    for (int j = 0; j < 256; j += 4) {
      float4 w4 = *(const float4*)(wrow + j);
#pragma unroll
      for (int rr = 0; rr < 8; rr++) {
        float4 x4 = *(const float4*)(x + rr * 256 + j);
        acc[rr] = fmaf(x4.x, w4.x, fmaf(x4.y, w4.y, fmaf(x4.z, w4.z, fmaf(x4.w, w4.w, acc[rr]))));
      }
    }
    __bf16* qhb = (__bf16*)(ws + WS_QHB);
#pragma unroll
    for (int rr = 0; rr < 8; rr++)
      qhb[(unsigned)(r0 + rr) * 256u + t] = (__bf16)(acc[rr] * 0.17677669529663687f);
  } else if (bid < 579) {
    int b2 = bid - 547; int n = b2 >> 4, tile = b2 & 15;
    int r0l = tile * 7; int cnt = 100 - r0l; if (cnt > 7) cnt = 7; if (cnt <= 0) return;
    int r0 = n * 100 + r0l;
    for (int i = t; i < cnt * 256; i += 256) x[i] = kfeat[(unsigned)r0 * 256u + i];
    __syncthreads();
    float ak[7], av[7]; float bk = ipb[256 + t], bv = ipb[512 + t];
#pragma unroll
    for (int rr = 0; rr < 7; rr++) { ak[rr] = bk; av[rr] = bv; }
    const float* wkr = ipw + (unsigned)(256 + t) * 256u;
    const float* wvr = ipw + (unsigned)(512 + t) * 256u;
    for (int j = 0; j < 256; j += 4) {
      float4 wk4 = *(const float4*)(wkr + j);
      float4 wv4 = *(const float4*)(wvr + j);
#pragma unroll
      for (int rr = 0; rr < 7; rr++) {
        float4 x4 = *(const float4*)(x + rr * 256 + j);
        ak[rr] = fmaf(x4.x, wk4.x, fmaf(x4.y, wk4.y, fmaf(x4.z, wk4.z, fmaf(x4.w, wk4.w, ak[rr]))));
        av[rr] = fmaf(x4.x, wv4.x, fmaf(x4.y, wv4.y, fmaf(x4.z, wv4.z, fmaf(x4.w, wv4.w, av[rr]))));
      }
    }
    for (int rr = 0; rr < 7; rr++) {
      if (rr < cnt) {
        ws[WS_KH + (unsigned)(r0 + rr) * 256u + t] = ak[rr];
        ws[WS_VH + (unsigned)(r0 + rr) * 256u + t] = av[rr];
      }
    }
  } else if (bid < 1379) {
    int r = (bid - 579) * 4 + (t >> 6);
    int u = t & 63;
    float p0 = qpos[r * 2 + 0], p1 = qpos[r * 2 + 1];
    __bf16* qeb = (__bf16*)(ws + WS_QEB);
    bf16x4 o;
#pragma unroll
    for (int j = 0; j < 4; j++) {
      int col = u * 4 + j;
      int c = col >> 7, i = (col & 127) >> 1;
      float p = c ? p1 : p0;
      float inv = exp2f((float)i * (-13.287712379549449f / 64.0f));
      float v = p * inv;
      o[j] = (__bf16)((col & 1) ? __cosf(v) : __sinf(v));
    }
    *(bf16x4*)(qeb + r * 256 + u * 4) = o;
  } else if (bid < 1395) {
    __shared__ float tile[64][65];
    int b = bid - 1379;
    int row0 = (b >> 2) * 64, col0 = (b & 3) * 64;
    int l = t & 63, gq = t >> 6;
#pragma unroll
    for (int i = 0; i < 16; i++) {
      int r = gq * 16 + i;
      tile[r][l] = ow[(unsigned)(row0 + r) * 256u + col0 + l];
    }
    __syncthreads();
#pragma unroll
    for (int i = 0; i < 16; i++) {
      int r = gq * 16 + i;
      ws[WS_OWT + (unsigned)(col0 + r) * 256u + row0 + l] = tile[l][r];
    }
  } else {
    __shared__ float tile[64][65];
    int b = bid - 1395;
    int row0 = (b / 5) * 64, col0 = (b % 5) * 64;
    int l = t & 63, gq = t >> 6;
#pragma unroll
    for (int i = 0; i < 16; i++) {
      int r = gq * 16 + i;
      int cin = col0 + l;
      tile[r][l] = (cin < 258) ? ew[(unsigned)(row0 + r) * 258u + cin] : 0.0f;
    }
    __syncthreads();
#pragma unroll
    for (int i = 0; i < 16; i++) {
      int r = gq * 16 + i;
      int j = col0 + r;
      if (j < 260) ws[WS_EWT + (unsigned)j * 256u + row0 + l] = tile[l][r];
    }
  }
}

// ---------------------------------------------------------------------------
// bias kernel (r13 verbatim — session best: 94.4us). Key-side fold, rot
// once/block, af[8][4] resident; reg-accumulated bias stores at kernel end;
// ONE barrier/tile via double-buffered qe+hid; T5 setprio on both MFMA
// clusters (wave-role split wq==0 gemm2 / wq==1 GEMM1 makes it pay, m218b).
// Register law (r1/r10/r14, thrice-measured): this formulation sits exactly
// at 128 VGPR / 2 waves/SIMD; ANY added persistent state spills (r14's
// 32-reg w2f hoist -> 48MB scratch, 94->110us). Occupancy is invariant to
// residency (r7/r12). Do not touch.
__global__ __launch_bounds__(512, 2) void bias_kernel(
    const float* __restrict__ pos_b1, const float* __restrict__ pos_b2,
    float* __restrict__ ws)
{
  __shared__ __align__(16) char qe_smem[2][32768];    // [64 q][512B] swizzled
  __shared__ __align__(16) char hid_smem[2][32768];   // [64 q][512B] swizzled
  __shared__ __align__(16) __bf16 keb_s[256];

  int bid = blockIdx.x;           // 0..999 = nk(200) x qgroup(5)
  int nk = bid / 5, g = bid - nk * 5;
  int n = nk / 100, k = nk - n * 100;
  int qbase = n * 1600 + g * 320;
  int t = threadIdx.x;
  int lane = t & 63, w = t >> 6;        // w 0..7
  int wc = w & 3, wq = w >> 2;          // c-quadrant, q-half
  int l15 = lane & 15, quad = lane >> 4;

  const __bf16* keb = (const __bf16*)(ws + WS_KEB) + (unsigned)nk * 264u;
  const __bf16* qeb = (const __bf16*)(ws + WS_QEB);
  const __bf16* w1b = (const __bf16*)(ws + WS_W1B);
  const __bf16* w2pb = (const __bf16*)(ws + WS_W2PB);
  __bf16* biasb = (__bf16*)(ws + WS_BIASB);

  if (t < 32) *(bf16x8*)(keb_s + t * 8) = *(const bf16x8*)(keb + t * 8);

  int sr = t >> 3, ssub = t & 7, sswz = (sr & 7) << 4;
  {
    const __bf16* src = qeb + (unsigned)(qbase + sr) * 256u + ssub * 32;
    char* dst = qe_smem[0] + sr * 512;
#pragma unroll
    for (int u = 0; u < 4; u++) {
      bf16x8 v = *(const bf16x8*)(src + u * 8);
      *(bf16x8*)(dst + ((ssub * 64 + u * 16) ^ sswz)) = v;
    }
  }

  int xm = (l15 & 7) << 4;
  int colx[8];
#pragma unroll
  for (int kc = 0; kc < 8; kc++) colx[kc] = ((kc * 64 + quad * 16) ^ xm);
  const __bf16* w1p = w1b + (unsigned)(wc * 64 + l15) * 256u + quad * 8;

  float b1a[4][4];
#pragma unroll
  for (int ct = 0; ct < 4; ct++)
#pragma unroll
    for (int r = 0; r < 4; r++) b1a[ct][r] = pos_b1[wc * 64 + ct * 16 + quad * 4 + r];
  float b2v[4];
#pragma unroll
  for (int r = 0; r < 4; r++) b2v[r] = pos_b2[(quad * 4 + r) & 7];

  f32x4 zero4; zero4[0] = 0.f; zero4[1] = 0.f; zero4[2] = 0.f; zero4[3] = 0.f;

  __syncthreads();   // keb_s + qe tile0 ready

  bf16x8 af[8][4];
#pragma unroll
  for (int kc = 0; kc < 8; kc++) {
    bf16x8 ke8 = *(const bf16x8*)(keb_s + kc * 32 + quad * 8);
#pragma unroll
    for (int ct = 0; ct < 4; ct++) {
      bf16x8 w8 = *(const bf16x8*)(w1p + ct * 4096 + kc * 32);
      bf16x8 a;
#pragma unroll
      for (int p2 = 0; p2 < 4; p2++) {
        float we = (float)w8[2 * p2], wo = (float)w8[2 * p2 + 1];
        float sk = (float)ke8[2 * p2], ck = (float)ke8[2 * p2 + 1];
        a[2 * p2]     = (__bf16)fmaf(wo, sk, -(we * ck));
        a[2 * p2 + 1] = (__bf16)fmaf(we, sk, wo * ck);
      }
      af[kc][ct] = a;
    }
  }

  unsigned long long bias_pk[5];

  auto gemm2 = [&](int tg) {
    bf16x8 w2f[8];
#pragma unroll
    for (int kc = 0; kc < 8; kc++)
      w2f[kc] = *(const bf16x8*)(w2pb + (unsigned)l15 * 256u + kc * 32 + quad * 8);
    int row = wc * 16 + l15;
    const char* hbase = hid_smem[tg & 1] + row * 512;
    int hxm = (l15 & 7) << 4;
    f32x4 acc2 = zero4;
    __builtin_amdgcn_s_setprio(1);    // T5: MFMA cluster
#pragma unroll
    for (int kc = 0; kc < 8; kc++) {
      bf16x8 hf = *(const bf16x8*)(hbase + ((kc * 64 + quad * 16) ^ hxm));
      acc2 = __builtin_amdgcn_mfma_f32_16x16x32_bf16(w2f[kc], hf, acc2, 0, 0, 0);
    }
    __builtin_amdgcn_s_setprio(0);
    unsigned lo = packbf(acc2[0] + b2v[0], acc2[1] + b2v[1]);
    unsigned hi = packbf(acc2[2] + b2v[2], acc2[3] + b2v[3]);
    return (unsigned long long)lo | ((unsigned long long)hi << 32);
  };

#pragma unroll
  for (int tt = 0; tt < 5; tt++) {
    bf16x8 qv[4];
    if (tt < 4) {
      const __bf16* src = qeb + (unsigned)(qbase + (tt + 1) * 64 + sr) * 256u + ssub * 32;
#pragma unroll
      for (int u = 0; u < 4; u++) qv[u] = *(const bf16x8*)(src + u * 8);
    }

    if (tt > 0 && wq == 0) bias_pk[tt - 1] = gemm2(tt - 1);

    f32x4 acc[4][2];
#pragma unroll
    for (int ct = 0; ct < 4; ct++)
#pragma unroll
      for (int nt = 0; nt < 2; nt++) acc[ct][nt] = zero4;

    __builtin_amdgcn_s_setprio(1);    // T5: GEMM1 MFMA cluster
#pragma unroll
    for (int kc = 0; kc < 8; kc++) {
#pragma unroll
      for (int nt = 0; nt < 2; nt++) {
        int row = wq * 32 + nt * 16 + l15;
        bf16x8 qf = *(const bf16x8*)(qe_smem[tt & 1] + row * 512 + colx[kc]);
        acc[0][nt] = __builtin_amdgcn_mfma_f32_16x16x32_bf16(af[kc][0], qf, acc[0][nt], 0, 0, 0);
        acc[1][nt] = __builtin_amdgcn_mfma_f32_16x16x32_bf16(af[kc][1], qf, acc[1][nt], 0, 0, 0);
        acc[2][nt] = __builtin_amdgcn_mfma_f32_16x16x32_bf16(af[kc][2], qf, acc[2][nt], 0, 0, 0);
        acc[3][nt] = __builtin_amdgcn_mfma_f32_16x16x32_bf16(af[kc][3], qf, acc[3][nt], 0, 0, 0);
      }
    }
    __builtin_amdgcn_s_setprio(0);

#pragma unroll
    for (int ct = 0; ct < 4; ct++) {
#pragma unroll
      for (int nt = 0; nt < 2; nt++) {
        int q = wq * 32 + nt * 16 + l15;
        unsigned lo = packbf(fmaxf(acc[ct][nt][0] + b1a[ct][0], 0.f),
                             fmaxf(acc[ct][nt][1] + b1a[ct][1], 0.f));
        unsigned hi = packbf(fmaxf(acc[ct][nt][2] + b1a[ct][2], 0.f),
                             fmaxf(acc[ct][nt][3] + b1a[ct][3], 0.f));
        int cbyte = wc * 128 + ct * 32 + quad * 8;
        char* p = hid_smem[tt & 1] + q * 512 + (cbyte ^ ((q & 7) << 4));
        *(unsigned long long*)p = (unsigned long long)lo | ((unsigned long long)hi << 32);
      }
    }

    if (tt < 4) {
      char* dst = qe_smem[(tt + 1) & 1] + sr * 512;
#pragma unroll
      for (int u = 0; u < 4; u++)
        *(bf16x8*)(dst + ((ssub * 64 + u * 16) ^ sswz)) = qv[u];
    }

    __syncthreads();
  }

  if (wq == 0) {
    bias_pk[4] = gemm2(4);
    if (quad < 2) {
      int row = wc * 16 + l15;
#pragma unroll
      for (int tg = 0; tg < 5; tg++) {
        int qg = qbase + tg * 64 + row;
        *(unsigned long long*)(biasb + (unsigned)qg * 896u + (unsigned)k * 8u + quad * 4)
            = bias_pk[tg];
      }
    }
  }
}

// ---------------------------------------------------------------------------
// attn kernel (r11 form): owT/ewT column reads; rdlane broadcast.
__global__ __launch_bounds__(256, 4) void attn_kernel(
    const float* __restrict__ qfeat, const float* __restrict__ qpos,
    const float* __restrict__ kpos,
    const float* __restrict__ out_b,
    const float* __restrict__ embed_b, const float* __restrict__ ptw,
    const float* __restrict__ ws, float* __restrict__ out)
{
  __shared__ float qh_s[4 * 8 * 36];
  __shared__ float attn_s[4 * 8 * 116];
  __shared__ float ctx_s[4 * 264];
  __shared__ float cat_s[4 * 264];
  __shared__ float aw_s[4 * 104];

  int bid = blockIdx.x;
  int qg0 = bid * 4;
  int n = bid / 400;
  int t = threadIdx.x;

  const __bf16* qhb = (const __bf16*)(ws + WS_QHB);
  const __bf16* biasb = (const __bf16*)(ws + WS_BIASB);
  const float* kh = ws + WS_KH;
  const float* vh = ws + WS_VH;

  for (int i = t; i < 1024; i += 256) {
    int q = i >> 8, c = i & 255;
    qh_s[(q * 8 + (c >> 5)) * 36 + (c & 31)] = (float)qhb[(unsigned)(qg0 + q) * 256u + c];
  }
  __syncthreads();

  for (int i = 0; i < 4; i++) {
    int p = t + i * 256;
    if (p < 800) {
      int k = p >> 3, h = p & 7;
      const float4* kf = (const float4*)(kh + (unsigned)(n * 100 + k) * 256u + h * 32);
      float4 kv[8];
#pragma unroll
      for (int dd = 0; dd < 8; dd++) kv[dd] = kf[dd];
#pragma unroll
      for (int q = 0; q < 4; q++) {
        const float4* qf = (const float4*)(qh_s + (q * 8 + h) * 36);
        float s = (float)biasb[((unsigned)(qg0 + q) * 112u + k) * 8u + h];
#pragma unroll
        for (int dd = 0; dd < 8; dd++) {
          float4 qv = qf[dd];
          s += kv[dd].x * qv.x + kv[dd].y * qv.y + kv[dd].z * qv.z + kv[dd].w * qv.w;
        }
        attn_s[(q * 8 + h) * 116 + k] = s;
      }
    }
  }
  __syncthreads();

  {
    int q = t >> 6, h = (t >> 3) & 7, j = t & 7;
    float* row = attn_s + (q * 8 + h) * 116;
    float mx = -1e30f;
    for (int k = j; k < 100; k += 8) mx = fmaxf(mx, row[k]);
    mx = fmaxf(mx, __shfl_xor(mx, 1, 8));
    mx = fmaxf(mx, __shfl_xor(mx, 2, 8));
    mx = fmaxf(mx, __shfl_xor(mx, 4, 8));
    float sum = 0.f;
    for (int k = j; k < 100; k += 8) { float e = __expf(row[k] - mx); row[k] = e; sum += e; }
    sum += __shfl_xor(sum, 1, 8);
    sum += __shfl_xor(sum, 2, 8);
    sum += __shfl_xor(sum, 4, 8);
    float inv = 1.0f / sum;
    for (int k = j; k < 100; k += 8) row[k] *= inv;
  }
  __syncthreads();

  for (int p = t; p < 416; p += 256) {
    int q = p / 104, k = p % 104;
    if (k < 100) {
      float s = 0.f;
#pragma unroll
      for (int h = 0; h < 8; h++) s += attn_s[(q * 8 + h) * 116 + k];
      aw_s[q * 104 + k] = s * 0.125f;
    }
  }
  {
    int c = t, h = c >> 5;
    float a0 = 0.f, a1 = 0.f, a2 = 0.f, a3 = 0.f;
    const float* vp = vh + (unsigned)(n * 100) * 256u + c;
    const float* r0 = attn_s + (0 * 8 + h) * 116;
    const float* r1 = attn_s + (1 * 8 + h) * 116;
    const float* r2 = attn_s + (2 * 8 + h) * 116;
    const float* r3 = attn_s + (3 * 8 + h) * 116;
#pragma unroll 4
    for (int k = 0; k < 100; k++) {
      float vv = vp[(unsigned)k * 256u];
      a0 = fmaf(r0[k], vv, a0);
      a1 = fmaf(r1[k], vv, a1);
      a2 = fmaf(r2[k], vv, a2);
      a3 = fmaf(r3[k], vv, a3);
    }
    ctx_s[0 * 264 + c] = a0; ctx_s[1 * 264 + c] = a1;
    ctx_s[2 * 264 + c] = a2; ctx_s[3 * 264 + c] = a3;
  }
  __syncthreads();

  if (t < 8) {
    int q = t >> 1, cd = t & 1;
    float qp = qpos[(qg0 + q) * 2 + cd];
    float s = 0.f;
    for (int k = 0; k < 100; k++)
      s = fmaf(aw_s[q * 104 + k], kpos[(n * 100 + k) * 2 + cd] - qp, s);
    float so = __shfl_xor(s, 1, 2);
    if (cd == 0) cat_s[q * 264 + 256] = ptw[0] * s + ptw[1] * so;
    else         cat_s[q * 264 + 257] = ptw[2] * so + ptw[3] * s;
  }

  {
    int c = t, lane = t & 63;
    float ob = out_b[c];
    float acc0 = ob, acc1 = ob, acc2 = ob, acc3 = ob;
    const float* wcol = ws + WS_OWT + c;
    for (int ch = 0; ch < 4; ch++) {
      float v0 = ctx_s[0 * 264 + ch * 64 + lane];
      float v1 = ctx_s[1 * 264 + ch * 64 + lane];
      float v2 = ctx_s[2 * 264 + ch * 64 + lane];
      float v3 = ctx_s[3 * 264 + ch * 64 + lane];
#pragma unroll 4
      for (int j4 = 0; j4 < 16; j4++) {
        int jg = ch * 64 + j4 * 4;
        float w0 = wcol[(unsigned)(jg + 0) * 256u];
        float w1 = wcol[(unsigned)(jg + 1) * 256u];
        float w2 = wcol[(unsigned)(jg + 2) * 256u];
        float w3 = wcol[(unsigned)(jg + 3) * 256u];
        int jb = j4 * 4;
        acc0 = fmaf(rdlane(v0, jb + 0), w0, acc0);
        acc1 = fmaf(rdlane(v1, jb + 0), w0, acc1);
        acc2 = fmaf(rdlane(v2, jb + 0), w0, acc2);
        acc3 = fmaf(rdlane(v3, jb + 0), w0, acc3);
        acc0 = fmaf(rdlane(v0, jb + 1), w1, acc0);
        acc1 = fmaf(rdlane(v1, jb + 1), w1, acc1);
        acc2 = fmaf(rdlane(v2, jb + 1), w1, acc2);
        acc3 = fmaf(rdlane(v3, jb + 1), w1, acc3);
        acc0 = fmaf(rdlane(v0, jb + 2), w2, acc0);
        acc1 = fmaf(rdlane(v1, jb + 2), w2, acc1);
        acc2 = fmaf(rdlane(v2, jb + 2), w2, acc2);
        acc3 = fmaf(rdlane(v3, jb + 2), w2, acc3);
        acc0 = fmaf(rdlane(v0, jb + 3), w3, acc0);
        acc1 = fmaf(rdlane(v1, jb + 3), w3, acc1);
        acc2 = fmaf(rdlane(v2, jb + 3), w3, acc2);
        acc3 = fmaf(rdlane(v3, jb + 3), w3, acc3);
      }
    }
    cat_s[0 * 264 + c] = fmaxf(qfeat[(unsigned)(qg0 + 0) * 256u + c] + acc0, 0.f);
    cat_s[1 * 264 + c] = fmaxf(qfeat[(unsigned)(qg0 + 1) * 256u + c] + acc1, 0.f);
    cat_s[2 * 264 + c] = fmaxf(qfeat[(unsigned)(qg0 + 2) * 256u + c] + acc2, 0.f);
    cat_s[3 * 264 + c] = fmaxf(qfeat[(unsigned)(qg0 + 3) * 256u + c] + acc3, 0.f);
  }
  __syncthreads();

  {
    int c = t, lane = t & 63;
    float eb = embed_b[c];
    float acc0 = eb, acc1 = eb, acc2 = eb, acc3 = eb;
    const float* ecol = ws + WS_EWT + c;
    for (int ch = 0; ch < 4; ch++) {
      float v0 = cat_s[0 * 264 + ch * 64 + lane];
      float v1 = cat_s[1 * 264 + ch * 64 + lane];
      float v2 = cat_s[2 * 264 + ch * 64 + lane];
      float v3 = cat_s[3 * 264 + ch * 64 + lane];
#pragma unroll 4
      for (int j4 = 0; j4 < 16; j4++) {
        int jg = ch * 64 + j4 * 4;
        float w0 = ecol[(unsigned)(jg + 0) * 256u];
        float w1 = ecol[(unsigned)(jg + 1) * 256u];
        float w2 = ecol[(unsigned)(jg + 2) * 256u];
        float w3 = ecol[(unsigned)(jg + 3) * 256u];
        int jb = j4 * 4;
        acc0 = fmaf(rdlane(v0, jb + 0), w0, acc0);
        acc1 = fmaf(rdlane(v1, jb + 0), w0, acc1);
        acc2 = fmaf(rdlane(v2, jb + 0), w0, acc2);
        acc3 = fmaf(rdlane(v3, jb + 0), w0, acc3);
        acc0 = fmaf(rdlane(v0, jb + 1), w1, acc0);
        acc1 = fmaf(rdlane(v1, jb + 1), w1, acc1);
        acc2 = fmaf(rdlane(v2, jb + 1), w1, acc2);
        acc3 = fmaf(rdlane(v3, jb + 1), w1, acc3);
        acc0 = fmaf(rdlane(v0, jb + 2), w2, acc0);
        acc1 = fmaf(rdlane(v1, jb + 2), w2, acc1);
        acc2 = fmaf(rdlane(v2, jb + 2), w2, acc2);
        acc3 = fmaf(rdlane(v3, jb + 2), w2, acc3);
        acc0 = fmaf(rdlane(v0, jb + 3), w3, acc0);
        acc1 = fmaf(rdlane(v1, jb + 3), w3, acc1);
        acc2 = fmaf(rdlane(v2, jb + 3), w3, acc2);
        acc3 = fmaf(rdlane(v3, jb + 3), w3, acc3);
      }
    }
    float wtx = ecol[256u * 256u];
    float wty = ecol[257u * 256u];
    acc0 += cat_s[0 * 264 + 256] * wtx + cat_s[0 * 264 + 257] * wty;
    acc1 += cat_s[1 * 264 + 256] * wtx + cat_s[1 * 264 + 257] * wty;
    acc2 += cat_s[2 * 264 + 256] * wtx + cat_s[2 * 264 + 257] * wty;
    acc3 += cat_s[3 * 264 + 256] * wtx + cat_s[3 * 264 + 257] * wty;
    out[(unsigned)(qg0 + 0) * 256u + c] = fmaxf(acc0, 0.f);
    out[(unsigned)(qg0 + 1) * 256u + c] = fmaxf(acc1, 0.f);
    out[(unsigned)(qg0 + 2) * 256u + c] = fmaxf(acc2, 0.f);
    out[(unsigned)(qg0 + 3) * 256u + c] = fmaxf(acc3, 0.f);
  }
}

// ---------------------------------------------------------------------------
extern "C" void kernel_launch(void* const* d_in, const int* in_sizes, int n_in,
                              void* d_out, int out_size, void* d_ws, size_t ws_size,
                              hipStream_t stream)
{
  const float* query_feature  = (const float*)d_in[0];
  const float* query_position = (const float*)d_in[1];
  const float* key_feature    = (const float*)d_in[2];
  const float* key_position   = (const float*)d_in[3];
  const float* in_proj_w      = (const float*)d_in[4];
  const float* in_proj_b      = (const float*)d_in[5];
  const float* out_proj_w     = (const float*)d_in[6];
  const float* out_proj_b     = (const float*)d_in[7];
  const float* pos_w1         = (const float*)d_in[8];
  const float* pos_b1         = (const float*)d_in[9];
  const float* pos_w2         = (const float*)d_in[10];
  const float* pos_b2         = (const float*)d_in[11];
  const float* pos_trans_w    = (const float*)d_in[12];
  const float* embed_w        = (const float*)d_in[13];
  const float* embed_b        = (const float*)d_in[14];
  float* ws  = (float*)d_ws;
  float* out = (float*)d_out;

  hipLaunchKernelGGL(prep_kernel, dim3(1415), dim3(256), 0, stream,
                     query_feature, key_feature, key_position, query_position,
                     in_proj_w, in_proj_b, pos_w1, pos_w2,
                     out_proj_w, embed_w, ws);
  hipLaunchKernelGGL(bias_kernel, dim3(1000), dim3(512), 0, stream,
                     pos_b1, pos_b2, ws);
  hipLaunchKernelGGL(attn_kernel, dim3(800), dim3(256), 0, stream,
                     query_feature, query_position, key_position,
                     out_proj_b, embed_b, pos_trans_w,
                     ws, out);
}